// Round 5
// baseline (613.700 us; speedup 1.0000x reference)
//
#include <hip/hip_runtime.h>

// AlphaCompositionShader: B=4,H=512,W=512,K=8.
// R4 = R3 with compile fix: nontemporal stores need a native clang vector
// type, not HIP_vector_type<float,4>.
// Software-pipelined grid-stride: 4 pixels/thread, prefetch pixel r+1's
// 12-load burst before computing/storing pixel r; NT stores for all outputs.
// Outputs concatenated in d_out (float32):
//   [0,4P) image | [4P,5P) depth | [5P,6P) label | [6P,38P) human

#define BKG_DEPTH 100.0f
#define KD 8
#define PPT 4   // pixels per thread

typedef float float4n __attribute__((ext_vector_type(4)));

struct Px {
    float4 c[KD];
    float  z[KD];
    int    l[KD];
};

__device__ __forceinline__ void load_px(const float4* __restrict__ pc,
                                        const float4* __restrict__ zb,
                                        const int4*   __restrict__ lb,
                                        int pix, Px& p)
{
#pragma unroll
    for (int k = 0; k < KD; ++k) p.c[k] = pc[(size_t)pix * KD + k];
    const float4 z0 = zb[(size_t)pix * 2 + 0];
    const float4 z1 = zb[(size_t)pix * 2 + 1];
    p.z[0]=z0.x; p.z[1]=z0.y; p.z[2]=z0.z; p.z[3]=z0.w;
    p.z[4]=z1.x; p.z[5]=z1.y; p.z[6]=z1.z; p.z[7]=z1.w;
    const int4 l0 = lb[(size_t)pix * 2 + 0];
    const int4 l1 = lb[(size_t)pix * 2 + 1];
    p.l[0]=l0.x; p.l[1]=l0.y; p.l[2]=l0.z; p.l[3]=l0.w;
    p.l[4]=l1.x; p.l[5]=l1.y; p.l[6]=l1.z; p.l[7]=l1.w;
}

__device__ __forceinline__ void nt_store4(float* addr, float x, float y, float z, float w)
{
    float4n v; v.x = x; v.y = y; v.z = z; v.w = w;
    __builtin_nontemporal_store(v, (float4n*)addr);
}

__device__ __forceinline__ void process_store(const Px& p, int pix, int P,
                                              float bg0, float bg1, float bg2,
                                              float* __restrict__ out)
{
    // ---- composite: back-to-front scan (k = K-1 .. 0)
    float r = bg0, g = bg1, b = bg2;
    float a = 0.0f, d = BKG_DEPTH, lab = (float)KD;
#pragma unroll
    for (int k = KD - 1; k >= 0; --k) {
        const float alpha = p.c[k].w;
        const float ia = 1.0f - alpha;
        r = p.c[k].x * alpha + r * ia;
        g = p.c[k].y * alpha + g * ia;
        b = p.c[k].z * alpha + b * ia;
        a = fmaxf(alpha, a);
        if (p.z[k] > 0.0f) d = p.z[k] * alpha + d * ia;
        if (!(p.z[k] < 0.0f) && alpha > 0.5f) lab = (float)p.l[k];
    }
    const float labv = (lab > (float)KD - 0.5f) ? -1.0f : lab;

    // ---- nontemporal stores for composite outputs
    nt_store4(out + (size_t)pix * 4, r, g, b, a);
    __builtin_nontemporal_store(d,    out + (size_t)4 * P + pix);
    __builtin_nontemporal_store(labv, out + (size_t)5 * P + pix);

    // ---- human images: per label n, front-most fragment with z>=0 && lbl==n
    float* outH = out + (size_t)6 * P + (size_t)pix * KD * 4;
#pragma unroll
    for (int n = 0; n < KD; ++n) {
        float4 gat = make_float4(0.0f, 0.0f, 0.0f, 0.0f);
#pragma unroll
        for (int k = KD - 1; k >= 0; --k) {
            if (!(p.z[k] < 0.0f) && p.l[k] == n) gat = p.c[k];
        }
        const float alpha = gat.w;
        const float ia = 1.0f - alpha;
        nt_store4(outH + n * 4,
                  gat.x * alpha + bg0 * ia,
                  gat.y * alpha + bg1 * ia,
                  gat.z * alpha + bg2 * ia,
                  alpha);
    }
}

__global__ __launch_bounds__(256) void alpha_comp_kernel(
    const float4* __restrict__ pc,
    const float4* __restrict__ zb,
    const int4*   __restrict__ lb,
    const float*  __restrict__ bg,
    float* __restrict__ out,
    int P)
{
    const int tid = blockIdx.x * blockDim.x + threadIdx.x;
    const int stride = P / PPT;              // 262144 threads
    if (tid >= stride) return;

    const float bg0 = bg[0], bg1 = bg[1], bg2 = bg[2];

    Px cur, nxt;
    load_px(pc, zb, lb, tid, cur);
#pragma unroll
    for (int r = 0; r < PPT; ++r) {
        if (r + 1 < PPT) load_px(pc, zb, lb, tid + (r + 1) * stride, nxt);
        process_store(cur, tid + r * stride, P, bg0, bg1, bg2, out);
        if (r + 1 < PPT) cur = nxt;
    }
}

extern "C" void kernel_launch(void* const* d_in, const int* in_sizes, int n_in,
                              void* d_out, int out_size, void* d_ws, size_t ws_size,
                              hipStream_t stream) {
    const float4* pc = (const float4*)d_in[0];   // pixel_colors (B,H,W,K,4) f32
    const float4* zb = (const float4*)d_in[1];   // zbuf (B,H,W,K) f32
    const int4*   lb = (const int4*)d_in[2];     // pixel_labels (B,H,W,K) i32
    const float*  bg = (const float*)d_in[3];    // background_color (3,) f32
    float* out = (float*)d_out;

    const int P = in_sizes[1] / KD;              // B*H*W = 1048576
    const int threads = P / PPT;                 // 262144
    const int block = 256;
    const int grid = threads / block;            // 1024
    alpha_comp_kernel<<<grid, block, 0, stream>>>(pc, zb, lb, bg, out, P);
}

// Round 6
// 355.062 us; speedup vs baseline: 1.7284x; 1.7284x over previous
//
#include <hip/hip_runtime.h>

// AlphaCompositionShader: B=4,H=512,W=512,K=8.
// R5: test the latency theory properly. R0-R2/R4 all compiled to VGPR<=64,
// meaning the compiler serialized loads into uses (~2-4 outstanding). Here:
// 2 pixels/thread, ALL 24 load instructions issued into registers before any
// consumption (forces ~130+ VGPR), plain cached stores (R4's NT stores caused
// 2.6x write amplification on the 128B-stride human store - reverted).
// Outputs concatenated in d_out (float32):
//   [0,4P) image | [4P,5P) depth | [5P,6P) label | [6P,38P) human

#define BKG_DEPTH 100.0f
#define KD 8
#define PPT 2   // pixels per thread (adjacent pair)

struct Px {
    float4 c[KD];
    float  z[KD];
    int    l[KD];
};

__device__ __forceinline__ void load_px(const float4* __restrict__ pc,
                                        const float4* __restrict__ zb,
                                        const int4*   __restrict__ lb,
                                        int pix, Px& p)
{
#pragma unroll
    for (int k = 0; k < KD; ++k) p.c[k] = pc[(size_t)pix * KD + k];
    const float4 z0 = zb[(size_t)pix * 2 + 0];
    const float4 z1 = zb[(size_t)pix * 2 + 1];
    p.z[0]=z0.x; p.z[1]=z0.y; p.z[2]=z0.z; p.z[3]=z0.w;
    p.z[4]=z1.x; p.z[5]=z1.y; p.z[6]=z1.z; p.z[7]=z1.w;
    const int4 l0 = lb[(size_t)pix * 2 + 0];
    const int4 l1 = lb[(size_t)pix * 2 + 1];
    p.l[0]=l0.x; p.l[1]=l0.y; p.l[2]=l0.z; p.l[3]=l0.w;
    p.l[4]=l1.x; p.l[5]=l1.y; p.l[6]=l1.z; p.l[7]=l1.w;
}

__device__ __forceinline__ void process_store(const Px& p, int pix, int P,
                                              float bg0, float bg1, float bg2,
                                              float* __restrict__ out)
{
    // ---- composite: back-to-front scan (k = K-1 .. 0)
    float r = bg0, g = bg1, b = bg2;
    float a = 0.0f, d = BKG_DEPTH, lab = (float)KD;
#pragma unroll
    for (int k = KD - 1; k >= 0; --k) {
        const float alpha = p.c[k].w;
        const float ia = 1.0f - alpha;
        r = p.c[k].x * alpha + r * ia;
        g = p.c[k].y * alpha + g * ia;
        b = p.c[k].z * alpha + b * ia;
        a = fmaxf(alpha, a);
        if (p.z[k] > 0.0f) d = p.z[k] * alpha + d * ia;
        if (!(p.z[k] < 0.0f) && alpha > 0.5f) lab = (float)p.l[k];
    }
    const float labv = (lab > (float)KD - 0.5f) ? -1.0f : lab;

    ((float4*)out)[pix] = make_float4(r, g, b, a);
    out[(size_t)4 * P + pix] = d;
    out[(size_t)5 * P + pix] = labv;

    // ---- human images: per label n, front-most fragment with z>=0 && lbl==n
    float4* outH = (float4*)(out + (size_t)6 * P) + (size_t)pix * KD;
#pragma unroll
    for (int n = 0; n < KD; ++n) {
        float4 gat = make_float4(0.0f, 0.0f, 0.0f, 0.0f);
#pragma unroll
        for (int k = KD - 1; k >= 0; --k) {
            if (!(p.z[k] < 0.0f) && p.l[k] == n) gat = p.c[k];
        }
        const float alpha = gat.w;
        const float ia = 1.0f - alpha;
        outH[n] = make_float4(gat.x * alpha + bg0 * ia,
                              gat.y * alpha + bg1 * ia,
                              gat.z * alpha + bg2 * ia,
                              alpha);
    }
}

__global__ __launch_bounds__(256) void alpha_comp_kernel(
    const float4* __restrict__ pc,
    const float4* __restrict__ zb,
    const int4*   __restrict__ lb,
    const float*  __restrict__ bg,
    float* __restrict__ out,
    int P)
{
    const int tid = blockIdx.x * blockDim.x + threadIdx.x;
    const int pix0 = tid * PPT;
    if (pix0 >= P) return;

    const float bg0 = bg[0], bg1 = bg[1], bg2 = bg[2];

    // ---- issue the ENTIRE 24-instruction load burst before any use
    Px p0, p1;
    load_px(pc, zb, lb, pix0,     p0);
    load_px(pc, zb, lb, pix0 + 1, p1);

    process_store(p0, pix0,     P, bg0, bg1, bg2, out);
    process_store(p1, pix0 + 1, P, bg0, bg1, bg2, out);
}

extern "C" void kernel_launch(void* const* d_in, const int* in_sizes, int n_in,
                              void* d_out, int out_size, void* d_ws, size_t ws_size,
                              hipStream_t stream) {
    const float4* pc = (const float4*)d_in[0];   // pixel_colors (B,H,W,K,4) f32
    const float4* zb = (const float4*)d_in[1];   // zbuf (B,H,W,K) f32
    const int4*   lb = (const int4*)d_in[2];     // pixel_labels (B,H,W,K) i32
    const float*  bg = (const float*)d_in[3];    // background_color (3,) f32
    float* out = (float*)d_out;

    const int P = in_sizes[1] / KD;              // B*H*W = 1048576
    const int threads = P / PPT;                 // 524288
    const int block = 256;
    const int grid = threads / block;            // 2048
    alpha_comp_kernel<<<grid, block, 0, stream>>>(pc, zb, lb, bg, out, P);
}